// Round 1
// baseline (506.696 us; speedup 1.0000x reference)
//
#include <hip/hip_runtime.h>

#define SEQK 512
#define NH 16
#define HD 64
#define RD 1024
#define BBATCH 32
#define QK_SCALE 0.125f        // 1/sqrt(64)
#define LOG2E 1.4426950408889634f

typedef unsigned short u16;
using bf16x8 = __attribute__((ext_vector_type(8))) short;
using f32x4  = __attribute__((ext_vector_type(4))) float;

__device__ __forceinline__ u16 f2bf(float f) {
  unsigned u = __float_as_uint(f);
  u += 0x7FFFu + ((u >> 16) & 1u);   // round-to-nearest-even
  return (u16)(u >> 16);
}
__device__ __forceinline__ float bf2f(u16 v) {
  return __uint_as_float(((unsigned)v) << 16);
}
// 2^x in one VALU op (inputs are pre-scaled by LOG2E, so no v_mul needed)
__device__ __forceinline__ float fexp2(float x) {
  float r;
  asm("v_exp_f32 %0, %1" : "=v"(r) : "v"(x));
  return r;
}

__device__ __forceinline__ void async_cp16(const void* g, void* l) {
  __builtin_amdgcn_global_load_lds(
      (__attribute__((address_space(1))) void*)(void*)g,
      (__attribute__((address_space(3))) void*)l,
      16, 0, 0);
}

// ---------------------------------------------------------------- convert
__global__ void convert_kernel(const float* __restrict__ hR,
                               const float* __restrict__ Wq, const float* __restrict__ Wk,
                               const float* __restrict__ Wv, const float* __restrict__ Wo,
                               u16* __restrict__ hR16,
                               u16* __restrict__ Wq16, u16* __restrict__ Wk16,
                               u16* __restrict__ Wv16, u16* __restrict__ Wo16) {
  size_t i4 = (size_t)blockIdx.x * blockDim.x + threadIdx.x;
  size_t e = i4 * 4;
  const float* src; u16* dst; size_t off;
  if (e < 16777216u) { src = hR; dst = hR16; off = e; }
  else {
    size_t r = e - 16777216u;
    int w = (int)(r >> 20);
    off = r & 1048575u;
    src = (w == 0 ? Wq : w == 1 ? Wk : w == 2 ? Wv : Wo);
    dst = (w == 0 ? Wq16 : w == 1 ? Wk16 : w == 2 ? Wv16 : Wo16);
  }
  float4 v = *(const float4*)(src + off);
  ushort4 o;
  o.x = f2bf(v.x); o.y = f2bf(v.y); o.z = f2bf(v.z); o.w = f2bf(v.w);
  *(ushort4*)(dst + off) = o;
}

// ---------------------------------------------------------------- R normalize
__global__ void rnorm_kernel(const float* __restrict__ R, float* __restrict__ Rn) {
  int row = blockIdx.x;
  int lane = threadIdx.x;
  float4 v = *(const float4*)(R + (size_t)row * 256 + lane * 4);
  float ss = v.x * v.x + v.y * v.y + v.z * v.z + v.w * v.w;
  for (int off = 32; off; off >>= 1) ss += __shfl_xor(ss, off);
  float s = 1.0f / fmaxf(sqrtf(ss), 1e-12f);
  float4 o = {v.x * s, v.y * s, v.z * s, v.w * s};
  *(float4*)(Rn + (size_t)row * 256 + lane * 4) = o;
}

// ---------------------------------------------------------------- sim = Rn @ Rn^T  (bf16 out)
__global__ void sim_kernel(const float* __restrict__ Rn, u16* __restrict__ sim16) {
  __shared__ float Rl[16 * 256];
  int i0 = blockIdx.x * 16;
  int t = threadIdx.x;
  #pragma unroll
  for (int i = 0; i < 4; i++) {
    int f = t + i * 256;
    *(float4*)&Rl[f * 4] = *(const float4*)(Rn + (size_t)i0 * 256 + f * 4);
  }
  __syncthreads();
  for (int jj = 0; jj < 2; jj++) {
    int j = jj * 256 + t;
    float acc[16];
    #pragma unroll
    for (int i = 0; i < 16; i++) acc[i] = 0.f;
    for (int c = 0; c < 64; c++) {
      float4 rv = *(const float4*)(Rn + (size_t)j * 256 + c * 4);
      #pragma unroll
      for (int i = 0; i < 16; i++) {
        float4 a = *(const float4*)&Rl[i * 256 + c * 4];
        acc[i] += a.x * rv.x + a.y * rv.y + a.z * rv.z + a.w * rv.w;
      }
    }
    #pragma unroll
    for (int i = 0; i < 16; i++) sim16[(size_t)(i0 + i) * 512 + j] = f2bf(acc[i]);
  }
}

// ---------------------------------------------------------------- GEMM (bf16 MFMA)
template <int MODE>
__global__ __launch_bounds__(256)
void gemm_kernel(const u16* __restrict__ A,
                 const u16* __restrict__ B0, const u16* __restrict__ B1,
                 const u16* __restrict__ B2,
                 u16* __restrict__ q16, u16* __restrict__ k16, u16* __restrict__ v16,
                 float* __restrict__ outF) {
  __shared__ u16 Alds[128 * 32];
  __shared__ u16 Blds[128 * 32];
  int tid = threadIdx.x;
  int wave = tid >> 6, lane = tid & 63;
  int wm = wave & 1, wn = wave >> 1;
  int lr = lane & 15, qd = lane >> 4;
  int mb = blockIdx.x * 128;
  int ny = blockIdx.y;

  const u16* Bmat;
  int nbmat;
  if (MODE == 0) {
    int wsel = ny >> 3;
    Bmat = (wsel == 0 ? B0 : wsel == 1 ? B1 : B2);
    nbmat = (ny & 7) * 128;
  } else {
    Bmat = B0;
    nbmat = ny * 128;
  }

  f32x4 zero = {0.f, 0.f, 0.f, 0.f};
  f32x4 acc[4][4];
  #pragma unroll
  for (int i = 0; i < 4; i++)
    #pragma unroll
    for (int j = 0; j < 4; j++) acc[i][j] = zero;

  for (int kb = 0; kb < 1024; kb += 32) {
    #pragma unroll
    for (int j = 0; j < 2; j++) {
      int r = (wave * 2 + j) * 16 + (lane >> 2);
      int c = (lane & 3) ^ ((r >> 1) & 3);
      async_cp16(A + (size_t)(mb + r) * 1024 + kb + c * 8,
                 &Alds[(wave * 2 + j) * 512]);
      async_cp16(Bmat + (size_t)(nbmat + r) * 1024 + kb + c * 8,
                 &Blds[(wave * 2 + j) * 512]);
    }
    __syncthreads();

    bf16x8 af[4], bf[4];
    #pragma unroll
    for (int mi = 0; mi < 4; mi++) {
      int ra = wm * 64 + mi * 16 + lr;
      af[mi] = *(const bf16x8*)&Alds[ra * 32 + ((qd ^ ((ra >> 1) & 3)) << 3)];
      int rb = wn * 64 + mi * 16 + lr;
      bf[mi] = *(const bf16x8*)&Blds[rb * 32 + ((qd ^ ((rb >> 1) & 3)) << 3)];
    }
    #pragma unroll
    for (int mi = 0; mi < 4; mi++)
      #pragma unroll
      for (int ni = 0; ni < 4; ni++)
        acc[mi][ni] = __builtin_amdgcn_mfma_f32_16x16x32_bf16(af[mi], bf[ni],
                                                              acc[mi][ni], 0, 0, 0);
    __syncthreads();
  }

  if (MODE == 0) {
    int wsel = ny >> 3;
    u16* dst = (wsel == 0 ? q16 : wsel == 1 ? k16 : v16);
    // Q gets 1/sqrt(D) * log2(e): scores come out in the exp2 domain, so the
    // attention softmax needs no per-element v_mul before v_exp.
    float scl = (wsel == 0) ? QK_SCALE * LOG2E : 1.0f;
    #pragma unroll
    for (int mi = 0; mi < 4; mi++) {
      int m = mb + wm * 64 + mi * 16 + qd * 4;
      int b = m >> 9, kk = m & 511;
      #pragma unroll
      for (int ni = 0; ni < 4; ni++) {
        int n = nbmat + wn * 64 + ni * 16 + lr;
        int h = n >> 6, d = n & 63;
        u16* p = dst + ((size_t)(b * 16 + h) * 512 + kk) * 64 + d;
        #pragma unroll
        for (int r = 0; r < 4; r++) p[(size_t)r * 64] = f2bf(acc[mi][ni][r] * scl);
      }
    }
  } else {
    #pragma unroll
    for (int mi = 0; mi < 4; mi++) {
      int m = mb + wm * 64 + mi * 16 + qd * 4;
      #pragma unroll
      for (int ni = 0; ni < 4; ni++) {
        int n = ny * 128 + wn * 64 + ni * 16 + lr;
        #pragma unroll
        for (int r = 0; r < 4; r++) outF[(size_t)(m + r) * 1024 + n] = acc[mi][ni][r];
      }
    }
  }
}

// ---------------------------------------------------------------- V transpose
__global__ void vtrans_kernel(const u16* __restrict__ v16, u16* __restrict__ vt16) {
  __shared__ u16 tile[64 * 72];
  int kt = blockIdx.x;
  int bh = blockIdx.y;
  int t = threadIdx.x;
  const u16* src = v16 + ((size_t)bh * 512 + kt * 64) * 64;
  #pragma unroll
  for (int j = 0; j < 2; j++) {
    int linear = j * 2048 + t * 8;
    int kr = linear >> 6, d0 = linear & 63;
    bf16x8 vv = *(const bf16x8*)(src + (size_t)kr * 64 + d0);
    #pragma unroll
    for (int e = 0; e < 8; e++) tile[kr * 72 + d0 + e] = (u16)vv[e];
  }
  __syncthreads();
  #pragma unroll
  for (int j = 0; j < 2; j++) {
    int linear = j * 2048 + t * 8;
    int dr = linear >> 6, k0 = linear & 63;
    bf16x8 ov;
    #pragma unroll
    for (int e = 0; e < 8; e++) ov[e] = (short)tile[(k0 + e) * 72 + dr];
    *(bf16x8*)(vt16 + ((size_t)bh * 64 + dr) * 512 + kt * 64 + k0) = ov;
  }
}

// ---------------------------------------------------------------- fused attention v4
// v3 bottleneck (rocprof): MfmaUtil 10%, VALUBusy 40% -> ~50% idle cycles.
// Cause: serial stage->drain->compute per chunk (2 barriers + exposed L2
// latency, the m233 "2-phase stall"). v4: K/V double-buffered in LDS; chunk
// ck+1's global_load_lds are issued BEFORE computing chunk ck, and the single
// __syncthreads() per chunk (vmcnt(0)+barrier) lands after ~3000cy of
// compute, so the drain is nearly free. Barriers: 8 -> 4 per block.
// LDS 80KB -> 2 blocks/CU (occupancy 3->2 accepted: the stall removed is
// intra-block, 12 waves/CU weren't hiding it).
// exp() sites: inputs pre-scaled by log2e (Q scale + ws), so each exp is a
// single v_exp_f32 (no v_mul) -> -32 VALU ops/chunk/lane.
__global__ __launch_bounds__(256, 2)
void attn_kernel(const u16* __restrict__ q16, const u16* __restrict__ k16,
                 const u16* __restrict__ vt16, const u16* __restrict__ sim16,
                 const float* __restrict__ wsim, u16* __restrict__ attn16) {
  __shared__ u16 Kbuf[2][128 * 64];    // [kl][d], 16B chunks XOR-swizzled by kl&7
  __shared__ u16 Vbuf[2][64 * 128];    // [d][kl], 16B chunks XOR-swizzled by d&15
  __shared__ u16 Plds[4 * 16 * 128];

  int id = blockIdx.x;
  int xcd = id & 7;
  int j = id >> 3;
  int qt = j & 7;
  int bh = xcd * 64 + (j >> 3);
  int b = bh >> 4, h = bh & 15;

  int tid = threadIdx.x;
  int wave = tid >> 6, lane = tid & 63;
  int lr = lane & 15, qd = lane >> 4;
  int qrb = qt * 64 + wave * 16;
  u16* Pw = &Plds[wave * 2048];

  const u16* qp = q16 + ((size_t)bh * 512 + qrb + lr) * 64 + qd * 8;
  bf16x8 aq0 = *(const bf16x8*)qp;
  bf16x8 aq1 = *(const bf16x8*)(qp + 32);

  float ws = wsim[h] * LOG2E;          // bias also moved to exp2 domain
  int row0 = qrb + qd * 4;

  f32x4 zero = {0.f, 0.f, 0.f, 0.f};
  f32x4 o[4];
  #pragma unroll
  for (int nt = 0; nt < 4; nt++) o[nt] = zero;
  float m_run[4] = {-1e30f, -1e30f, -1e30f, -1e30f};
  float l_run[4] = {0.f, 0.f, 0.f, 0.f};

  const u16* kbase = k16 + (size_t)bh * 512 * 64;
  const u16* vbase = vt16 + (size_t)bh * 64 * 512;

  // stage chunk ck (128 k) into buffer nb — issue only, no wait
  auto stage = [&](int nb, int ck) {
    int k0 = ck * 128;
    #pragma unroll
    for (int jj = 0; jj < 4; jj++) {
      int rbase = wave * 32 + jj * 8;
      int r = rbase + (lane >> 3);
      int c = (lane & 7) ^ (r & 7);
      async_cp16(kbase + (size_t)(k0 + r) * 64 + c * 8, &Kbuf[nb][rbase * 64]);
    }
    #pragma unroll
    for (int jj = 0; jj < 4; jj++) {
      int dbase = wave * 16 + jj * 4;
      int d = dbase + (lane >> 4);
      int c = (lane & 15) ^ (d & 15);
      async_cp16(vbase + (size_t)d * 512 + k0 + c * 8, &Vbuf[nb][dbase * 128]);
    }
  };

  stage(0, 0);
  __syncthreads();                     // prologue: chunk 0 resident

  int cb = 0;
  for (int ck = 0; ck < 4; ck++) {
    if (ck < 3) stage(cb ^ 1, ck + 1);   // prefetch flies during compute below
    int k0 = ck * 128;
    const u16* Kc = &Kbuf[cb][0];
    const u16* Vc = &Vbuf[cb][0];

    // ---- QK^T, bias (bf16 global) as C-init
    f32x4 s[8];
    #pragma unroll
    for (int jt = 0; jt < 8; jt++) {
      int kl = jt * 16 + lr;
      ushort4 b4 = *(const ushort4*)(sim16 + (size_t)(k0 + kl) * 512 + row0);
      f32x4 t = {ws * bf2f(b4.x), ws * bf2f(b4.y), ws * bf2f(b4.z), ws * bf2f(b4.w)};
      const u16* krow = Kc + kl * 64;
      int sw = kl & 7;
      bf16x8 kf0 = *(const bf16x8*)(krow + ((qd ^ sw) << 3));
      bf16x8 kf1 = *(const bf16x8*)(krow + (((qd + 4) ^ sw) << 3));
      t = __builtin_amdgcn_mfma_f32_16x16x32_bf16(aq0, kf0, t, 0, 0, 0);
      t = __builtin_amdgcn_mfma_f32_16x16x32_bf16(aq1, kf1, t, 0, 0, 0);
      s[jt] = t;
    }
    // ---- online softmax update (exp2 domain)
    float mnew[4], alpha[4], csum[4];
    #pragma unroll
    for (int r = 0; r < 4; r++) {
      float m = s[0][r];
      #pragma unroll
      for (int jt = 1; jt < 8; jt++) m = fmaxf(m, s[jt][r]);
      m = fmaxf(m, __shfl_xor(m, 1));
      m = fmaxf(m, __shfl_xor(m, 2));
      m = fmaxf(m, __shfl_xor(m, 4));
      m = fmaxf(m, __shfl_xor(m, 8));
      mnew[r] = fmaxf(m_run[r], m);
      alpha[r] = fexp2(m_run[r] - mnew[r]);
      m_run[r] = mnew[r];
      csum[r] = 0.f;
    }
    #pragma unroll
    for (int jt = 0; jt < 8; jt++)
      #pragma unroll
      for (int r = 0; r < 4; r++) {
        float e = fexp2(s[jt][r] - mnew[r]);
        s[jt][r] = e;
        csum[r] += e;
      }
    #pragma unroll
    for (int r = 0; r < 4; r++) {
      float t = csum[r];
      t += __shfl_xor(t, 1); t += __shfl_xor(t, 2);
      t += __shfl_xor(t, 4); t += __shfl_xor(t, 8);
      l_run[r] = l_run[r] * alpha[r] + t;
    }
    // ---- P -> per-wave LDS (XOR chunk swizzle), no barrier
    #pragma unroll
    for (int jt = 0; jt < 8; jt++) {
      int c = jt * 2 + (lr >> 3);
      int e = lr & 7;
      #pragma unroll
      for (int r = 0; r < 4; r++) {
        int row = qd * 4 + r;
        Pw[row * 128 + ((c ^ row) & 15) * 8 + e] = f2bf(s[jt][r]);
      }
    }
    // ---- rescale O, PV from LDS
    #pragma unroll
    for (int nt = 0; nt < 4; nt++)
      #pragma unroll
      for (int r = 0; r < 4; r++) o[nt][r] *= alpha[r];
    #pragma unroll
    for (int ks = 0; ks < 4; ks++) {
      bf16x8 ap = *(const bf16x8*)&Pw[lr * 128 + (((ks * 4 + qd) ^ lr) & 15) * 8];
      #pragma unroll
      for (int nt = 0; nt < 4; nt++) {
        int d = nt * 16 + lr;
        bf16x8 vf = *(const bf16x8*)&Vc[d * 128 + (((ks * 4 + qd) ^ (d & 15)) << 3)];
        o[nt] = __builtin_amdgcn_mfma_f32_16x16x32_bf16(ap, vf, o[nt], 0, 0, 0);
      }
    }
    if (ck < 3) __syncthreads();       // drain prefetch (landed during compute) + swap
    cb ^= 1;
  }

  // ---- epilogue: normalize, transpose via per-wave LDS, coalesced 16B stores
  float inv[4];
  #pragma unroll
  for (int r = 0; r < 4; r++) inv[r] = 1.0f / l_run[r];
  u16* Ow = Pw;   // reuse per-wave region: [16 rows][64 d] stride 72
  #pragma unroll
  for (int nt = 0; nt < 4; nt++)
    #pragma unroll
    for (int r = 0; r < 4; r++)
      Ow[(qd * 4 + r) * 72 + nt * 16 + lr] = f2bf(o[nt][r] * inv[r]);
  #pragma unroll
  for (int it = 0; it < 2; it++) {
    int row = it * 8 + (lane >> 3);
    int seg = lane & 7;
    bf16x8 val = *(const bf16x8*)&Ow[row * 72 + seg * 8];
    *(bf16x8*)(attn16 + ((size_t)b * 512 + qrb + row) * 1024 + h * 64 + seg * 8) = val;
  }
}

// ---------------------------------------------------------------- launch
extern "C" void kernel_launch(void* const* d_in, const int* in_sizes, int n_in,
                              void* d_out, int out_size, void* d_ws, size_t ws_size,
                              hipStream_t stream) {
  const float* hR  = (const float*)d_in[0];
  const float* R   = (const float*)d_in[1];
  const float* Wq  = (const float*)d_in[2];
  const float* Wk  = (const float*)d_in[3];
  const float* Wv  = (const float*)d_in[4];
  const float* Wo  = (const float*)d_in[5];
  const float* wsm = (const float*)d_in[6];
  float* out = (float*)d_out;

  const size_t NE = 16777216;   // 16384 x 1024
  u16* ws16   = (u16*)d_ws;
  u16* hR16   = ws16;
  u16* attn16 = ws16;           // reuses hR16 (consumed by QKV GEMM)
  u16* q16    = ws16 + NE;
  u16* k16    = ws16 + 2 * NE;
  u16* v16    = ws16 + 3 * NE;
  u16* vt16   = ws16 + 4 * NE;
  u16* Wq16   = ws16 + 5 * NE;
  u16* Wk16   = Wq16 + 1048576;
  u16* Wv16   = Wk16 + 1048576;
  u16* Wo16   = Wv16 + 1048576;
  u16* sim16  = Wo16 + 1048576;              // 512*512 bf16
  float* Rn   = (float*)(sim16 + 262144);    // 512*256 fp32

  convert_kernel<<<20480, 256, 0, stream>>>(hR, Wq, Wk, Wv, Wo,
                                            hR16, Wq16, Wk16, Wv16, Wo16);
  rnorm_kernel<<<512, 64, 0, stream>>>(R, Rn);
  sim_kernel<<<32, 256, 0, stream>>>(Rn, sim16);
  gemm_kernel<0><<<dim3(128, 24), 256, 0, stream>>>(hR16, Wq16, Wk16, Wv16,
                                                    q16, k16, v16, nullptr);
  vtrans_kernel<<<dim3(8, 512), 256, 0, stream>>>(v16, vt16);
  attn_kernel<<<4096, 256, 0, stream>>>(q16, k16, vt16, sim16, wsm, attn16);
  gemm_kernel<1><<<dim3(128, 8), 256, 0, stream>>>(attn16, Wo16, nullptr, nullptr,
                                                   nullptr, nullptr, nullptr, out);
}

// Round 2
// 498.719 us; speedup vs baseline: 1.0160x; 1.0160x over previous
//
#include <hip/hip_runtime.h>

#define SEQK 512
#define NH 16
#define HD 64
#define RD 1024
#define BBATCH 32
#define QK_SCALE 0.125f        // 1/sqrt(64)
#define LOG2E 1.4426950408889634f

typedef unsigned short u16;
using bf16x8 = __attribute__((ext_vector_type(8))) short;
using f32x4  = __attribute__((ext_vector_type(4))) float;

__device__ __forceinline__ u16 f2bf(float f) {
  unsigned u = __float_as_uint(f);
  u += 0x7FFFu + ((u >> 16) & 1u);   // round-to-nearest-even
  return (u16)(u >> 16);
}
__device__ __forceinline__ float bf2f(u16 v) {
  return __uint_as_float(((unsigned)v) << 16);
}
// 2^x in one VALU op (inputs are pre-scaled by LOG2E, so no v_mul needed)
__device__ __forceinline__ float fexp2(float x) {
  float r;
  asm("v_exp_f32 %0, %1" : "=v"(r) : "v"(x));
  return r;
}

__device__ __forceinline__ void async_cp16(const void* g, void* l) {
  __builtin_amdgcn_global_load_lds(
      (__attribute__((address_space(1))) void*)(void*)g,
      (__attribute__((address_space(3))) void*)l,
      16, 0, 0);
}

// ---------------------------------------------------------------- convert
__global__ void convert_kernel(const float* __restrict__ hR,
                               const float* __restrict__ Wq, const float* __restrict__ Wk,
                               const float* __restrict__ Wv, const float* __restrict__ Wo,
                               u16* __restrict__ hR16,
                               u16* __restrict__ Wq16, u16* __restrict__ Wk16,
                               u16* __restrict__ Wv16, u16* __restrict__ Wo16) {
  size_t i4 = (size_t)blockIdx.x * blockDim.x + threadIdx.x;
  size_t e = i4 * 4;
  const float* src; u16* dst; size_t off;
  if (e < 16777216u) { src = hR; dst = hR16; off = e; }
  else {
    size_t r = e - 16777216u;
    int w = (int)(r >> 20);
    off = r & 1048575u;
    src = (w == 0 ? Wq : w == 1 ? Wk : w == 2 ? Wv : Wo);
    dst = (w == 0 ? Wq16 : w == 1 ? Wk16 : w == 2 ? Wv16 : Wo16);
  }
  float4 v = *(const float4*)(src + off);
  ushort4 o;
  o.x = f2bf(v.x); o.y = f2bf(v.y); o.z = f2bf(v.z); o.w = f2bf(v.w);
  *(ushort4*)(dst + off) = o;
}

// ---------------------------------------------------------------- R normalize
__global__ void rnorm_kernel(const float* __restrict__ R, float* __restrict__ Rn) {
  int row = blockIdx.x;
  int lane = threadIdx.x;
  float4 v = *(const float4*)(R + (size_t)row * 256 + lane * 4);
  float ss = v.x * v.x + v.y * v.y + v.z * v.z + v.w * v.w;
  for (int off = 32; off; off >>= 1) ss += __shfl_xor(ss, off);
  float s = 1.0f / fmaxf(sqrtf(ss), 1e-12f);
  float4 o = {v.x * s, v.y * s, v.z * s, v.w * s};
  *(float4*)(Rn + (size_t)row * 256 + lane * 4) = o;
}

// ---------------------------------------------------------------- sim = Rn @ Rn^T  (bf16 out)
__global__ void sim_kernel(const float* __restrict__ Rn, u16* __restrict__ sim16) {
  __shared__ float Rl[16 * 256];
  int i0 = blockIdx.x * 16;
  int t = threadIdx.x;
  #pragma unroll
  for (int i = 0; i < 4; i++) {
    int f = t + i * 256;
    *(float4*)&Rl[f * 4] = *(const float4*)(Rn + (size_t)i0 * 256 + f * 4);
  }
  __syncthreads();
  for (int jj = 0; jj < 2; jj++) {
    int j = jj * 256 + t;
    float acc[16];
    #pragma unroll
    for (int i = 0; i < 16; i++) acc[i] = 0.f;
    for (int c = 0; c < 64; c++) {
      float4 rv = *(const float4*)(Rn + (size_t)j * 256 + c * 4);
      #pragma unroll
      for (int i = 0; i < 16; i++) {
        float4 a = *(const float4*)&Rl[i * 256 + c * 4];
        acc[i] += a.x * rv.x + a.y * rv.y + a.z * rv.z + a.w * rv.w;
      }
    }
    #pragma unroll
    for (int i = 0; i < 16; i++) sim16[(size_t)(i0 + i) * 512 + j] = f2bf(acc[i]);
  }
}

// ---------------------------------------------------------------- GEMM (bf16 MFMA)
template <int MODE>
__global__ __launch_bounds__(256)
void gemm_kernel(const u16* __restrict__ A,
                 const u16* __restrict__ B0, const u16* __restrict__ B1,
                 const u16* __restrict__ B2,
                 u16* __restrict__ q16, u16* __restrict__ k16, u16* __restrict__ v16,
                 float* __restrict__ outF) {
  __shared__ u16 Alds[128 * 32];
  __shared__ u16 Blds[128 * 32];
  int tid = threadIdx.x;
  int wave = tid >> 6, lane = tid & 63;
  int wm = wave & 1, wn = wave >> 1;
  int lr = lane & 15, qd = lane >> 4;
  int mb = blockIdx.x * 128;
  int ny = blockIdx.y;

  const u16* Bmat;
  int nbmat;
  if (MODE == 0) {
    int wsel = ny >> 3;
    Bmat = (wsel == 0 ? B0 : wsel == 1 ? B1 : B2);
    nbmat = (ny & 7) * 128;
  } else {
    Bmat = B0;
    nbmat = ny * 128;
  }

  f32x4 zero = {0.f, 0.f, 0.f, 0.f};
  f32x4 acc[4][4];
  #pragma unroll
  for (int i = 0; i < 4; i++)
    #pragma unroll
    for (int j = 0; j < 4; j++) acc[i][j] = zero;

  for (int kb = 0; kb < 1024; kb += 32) {
    #pragma unroll
    for (int j = 0; j < 2; j++) {
      int r = (wave * 2 + j) * 16 + (lane >> 2);
      int c = (lane & 3) ^ ((r >> 1) & 3);
      async_cp16(A + (size_t)(mb + r) * 1024 + kb + c * 8,
                 &Alds[(wave * 2 + j) * 512]);
      async_cp16(Bmat + (size_t)(nbmat + r) * 1024 + kb + c * 8,
                 &Blds[(wave * 2 + j) * 512]);
    }
    __syncthreads();

    bf16x8 af[4], bf[4];
    #pragma unroll
    for (int mi = 0; mi < 4; mi++) {
      int ra = wm * 64 + mi * 16 + lr;
      af[mi] = *(const bf16x8*)&Alds[ra * 32 + ((qd ^ ((ra >> 1) & 3)) << 3)];
      int rb = wn * 64 + mi * 16 + lr;
      bf[mi] = *(const bf16x8*)&Blds[rb * 32 + ((qd ^ ((rb >> 1) & 3)) << 3)];
    }
    #pragma unroll
    for (int mi = 0; mi < 4; mi++)
      #pragma unroll
      for (int ni = 0; ni < 4; ni++)
        acc[mi][ni] = __builtin_amdgcn_mfma_f32_16x16x32_bf16(af[mi], bf[ni],
                                                              acc[mi][ni], 0, 0, 0);
    __syncthreads();
  }

  if (MODE == 0) {
    int wsel = ny >> 3;
    u16* dst = (wsel == 0 ? q16 : wsel == 1 ? k16 : v16);
    // Q gets 1/sqrt(D) * log2(e): scores come out in the exp2 domain, so the
    // attention softmax needs no per-element v_mul before v_exp.
    float scl = (wsel == 0) ? QK_SCALE * LOG2E : 1.0f;
    #pragma unroll
    for (int mi = 0; mi < 4; mi++) {
      int m = mb + wm * 64 + mi * 16 + qd * 4;
      int b = m >> 9, kk = m & 511;
      #pragma unroll
      for (int ni = 0; ni < 4; ni++) {
        int n = nbmat + wn * 64 + ni * 16 + lr;
        int h = n >> 6, d = n & 63;
        u16* p = dst + ((size_t)(b * 16 + h) * 512 + kk) * 64 + d;
        #pragma unroll
        for (int r = 0; r < 4; r++) p[(size_t)r * 64] = f2bf(acc[mi][ni][r] * scl);
      }
    }
  } else {
    #pragma unroll
    for (int mi = 0; mi < 4; mi++) {
      int m = mb + wm * 64 + mi * 16 + qd * 4;
      #pragma unroll
      for (int ni = 0; ni < 4; ni++) {
        int n = ny * 128 + wn * 64 + ni * 16 + lr;
        #pragma unroll
        for (int r = 0; r < 4; r++) outF[(size_t)(m + r) * 1024 + n] = acc[mi][ni][r];
      }
    }
  }
}

// ---------------------------------------------------------------- V transpose
__global__ void vtrans_kernel(const u16* __restrict__ v16, u16* __restrict__ vt16) {
  __shared__ u16 tile[64 * 72];
  int kt = blockIdx.x;
  int bh = blockIdx.y;
  int t = threadIdx.x;
  const u16* src = v16 + ((size_t)bh * 512 + kt * 64) * 64;
  #pragma unroll
  for (int j = 0; j < 2; j++) {
    int linear = j * 2048 + t * 8;
    int kr = linear >> 6, d0 = linear & 63;
    bf16x8 vv = *(const bf16x8*)(src + (size_t)kr * 64 + d0);
    #pragma unroll
    for (int e = 0; e < 8; e++) tile[kr * 72 + d0 + e] = (u16)vv[e];
  }
  __syncthreads();
  #pragma unroll
  for (int j = 0; j < 2; j++) {
    int linear = j * 2048 + t * 8;
    int dr = linear >> 6, k0 = linear & 63;
    bf16x8 ov;
    #pragma unroll
    for (int e = 0; e < 8; e++) ov[e] = (short)tile[(k0 + e) * 72 + dr];
    *(bf16x8*)(vt16 + ((size_t)bh * 64 + dr) * 512 + kt * 64 + k0) = ov;
  }
}

// ---------------------------------------------------------------- fused attention v5
// v4 post-mortem: prefetch gave ZERO overlap because vmcnt is a FIFO — the
// sim16 bias loads were issued AFTER the stage's global_load_lds, so the
// first bias use forced draining the whole prefetch (m135 semantics).
// v5: bias raw loads are issued BEFORE the stage (pinned by sched_barrier),
// so the bias wait is vmcnt(8) and the 8 stage loads stay in flight across
// the entire QK^T+softmax+PV phase (T4 counted-vmcnt). Single barrier per
// chunk drains loads that already landed. s_setprio(1) around MFMA clusters
// (T5): 8 waves/CU at different phases -> scheduler has roles to arbitrate.
__global__ __launch_bounds__(256, 2)
void attn_kernel(const u16* __restrict__ q16, const u16* __restrict__ k16,
                 const u16* __restrict__ vt16, const u16* __restrict__ sim16,
                 const float* __restrict__ wsim, u16* __restrict__ attn16) {
  __shared__ u16 Kbuf[2][128 * 64];    // [kl][d], 16B chunks XOR-swizzled by kl&7
  __shared__ u16 Vbuf[2][64 * 128];    // [d][kl], 16B chunks XOR-swizzled by d&15
  __shared__ u16 Plds[4 * 16 * 128];

  int id = blockIdx.x;
  int xcd = id & 7;
  int j = id >> 3;
  int qt = j & 7;
  int bh = xcd * 64 + (j >> 3);
  int b = bh >> 4, h = bh & 15;

  int tid = threadIdx.x;
  int wave = tid >> 6, lane = tid & 63;
  int lr = lane & 15, qd = lane >> 4;
  int qrb = qt * 64 + wave * 16;
  u16* Pw = &Plds[wave * 2048];

  const u16* qp = q16 + ((size_t)bh * 512 + qrb + lr) * 64 + qd * 8;
  bf16x8 aq0 = *(const bf16x8*)qp;
  bf16x8 aq1 = *(const bf16x8*)(qp + 32);

  float ws = wsim[h] * LOG2E;          // bias also in exp2 domain
  int row0 = qrb + qd * 4;

  f32x4 zero = {0.f, 0.f, 0.f, 0.f};
  f32x4 o[4];
  #pragma unroll
  for (int nt = 0; nt < 4; nt++) o[nt] = zero;
  float m_run[4] = {-1e30f, -1e30f, -1e30f, -1e30f};
  float l_run[4] = {0.f, 0.f, 0.f, 0.f};

  const u16* kbase = k16 + (size_t)bh * 512 * 64;
  const u16* vbase = vt16 + (size_t)bh * 64 * 512;

  // stage chunk ck (128 k) into buffer nb — issue only, no wait
  auto stage = [&](int nb, int ck) {
    int k0 = ck * 128;
    #pragma unroll
    for (int jj = 0; jj < 4; jj++) {
      int rbase = wave * 32 + jj * 8;
      int r = rbase + (lane >> 3);
      int c = (lane & 7) ^ (r & 7);
      async_cp16(kbase + (size_t)(k0 + r) * 64 + c * 8, &Kbuf[nb][rbase * 64]);
    }
    #pragma unroll
    for (int jj = 0; jj < 4; jj++) {
      int dbase = wave * 16 + jj * 4;
      int d = dbase + (lane >> 4);
      int c = (lane & 15) ^ (d & 15);
      async_cp16(vbase + (size_t)d * 512 + k0 + c * 8, &Vbuf[nb][dbase * 128]);
    }
  };

  stage(0, 0);
  __syncthreads();                     // prologue: chunk 0 resident

  int cb = 0;
  for (int ck = 0; ck < 4; ck++) {
    int k0 = ck * 128;

    // ---- bias raw loads FIRST (oldest in vmcnt queue): waiting on them
    //      leaves the stage loads below still in flight.
    ushort4 braw[8];
    #pragma unroll
    for (int jt = 0; jt < 8; jt++) {
      int kl = jt * 16 + lr;
      braw[jt] = *(const ushort4*)(sim16 + (size_t)(k0 + kl) * 512 + row0);
    }
    __builtin_amdgcn_sched_barrier(0); // pin: bias loads must precede stage
    if (ck < 3) stage(cb ^ 1, ck + 1); // prefetch flies during compute below

    const u16* Kc = &Kbuf[cb][0];
    const u16* Vc = &Vbuf[cb][0];

    // ---- QK^T, bias as C-init
    __builtin_amdgcn_s_setprio(1);
    f32x4 s[8];
    #pragma unroll
    for (int jt = 0; jt < 8; jt++) {
      int kl = jt * 16 + lr;
      ushort4 b4 = braw[jt];
      f32x4 t = {ws * bf2f(b4.x), ws * bf2f(b4.y), ws * bf2f(b4.z), ws * bf2f(b4.w)};
      const u16* krow = Kc + kl * 64;
      int sw = kl & 7;
      bf16x8 kf0 = *(const bf16x8*)(krow + ((qd ^ sw) << 3));
      bf16x8 kf1 = *(const bf16x8*)(krow + (((qd + 4) ^ sw) << 3));
      t = __builtin_amdgcn_mfma_f32_16x16x32_bf16(aq0, kf0, t, 0, 0, 0);
      t = __builtin_amdgcn_mfma_f32_16x16x32_bf16(aq1, kf1, t, 0, 0, 0);
      s[jt] = t;
    }
    __builtin_amdgcn_s_setprio(0);

    // ---- online softmax update (exp2 domain)
    float mnew[4], alpha[4], csum[4];
    #pragma unroll
    for (int r = 0; r < 4; r++) {
      float m = s[0][r];
      #pragma unroll
      for (int jt = 1; jt < 8; jt++) m = fmaxf(m, s[jt][r]);
      m = fmaxf(m, __shfl_xor(m, 1));
      m = fmaxf(m, __shfl_xor(m, 2));
      m = fmaxf(m, __shfl_xor(m, 4));
      m = fmaxf(m, __shfl_xor(m, 8));
      mnew[r] = fmaxf(m_run[r], m);
      alpha[r] = fexp2(m_run[r] - mnew[r]);
      m_run[r] = mnew[r];
      csum[r] = 0.f;
    }
    #pragma unroll
    for (int jt = 0; jt < 8; jt++)
      #pragma unroll
      for (int r = 0; r < 4; r++) {
        float e = fexp2(s[jt][r] - mnew[r]);
        s[jt][r] = e;
        csum[r] += e;
      }
    #pragma unroll
    for (int r = 0; r < 4; r++) {
      float t = csum[r];
      t += __shfl_xor(t, 1); t += __shfl_xor(t, 2);
      t += __shfl_xor(t, 4); t += __shfl_xor(t, 8);
      l_run[r] = l_run[r] * alpha[r] + t;
    }
    // ---- P -> per-wave LDS (XOR chunk swizzle), no barrier
    #pragma unroll
    for (int jt = 0; jt < 8; jt++) {
      int c = jt * 2 + (lr >> 3);
      int e = lr & 7;
      #pragma unroll
      for (int r = 0; r < 4; r++) {
        int row = qd * 4 + r;
        Pw[row * 128 + ((c ^ row) & 15) * 8 + e] = f2bf(s[jt][r]);
      }
    }
    // ---- rescale O, PV from LDS
    #pragma unroll
    for (int nt = 0; nt < 4; nt++)
      #pragma unroll
      for (int r = 0; r < 4; r++) o[nt][r] *= alpha[r];
    __builtin_amdgcn_s_setprio(1);
    #pragma unroll
    for (int ks = 0; ks < 4; ks++) {
      bf16x8 ap = *(const bf16x8*)&Pw[lr * 128 + (((ks * 4 + qd) ^ lr) & 15) * 8];
      #pragma unroll
      for (int nt = 0; nt < 4; nt++) {
        int d = nt * 16 + lr;
        bf16x8 vf = *(const bf16x8*)&Vc[d * 128 + (((ks * 4 + qd) ^ (d & 15)) << 3)];
        o[nt] = __builtin_amdgcn_mfma_f32_16x16x32_bf16(ap, vf, o[nt], 0, 0, 0);
      }
    }
    __builtin_amdgcn_s_setprio(0);
    if (ck < 3) __syncthreads();       // drain prefetch (landed during compute) + swap
    cb ^= 1;
  }

  // ---- epilogue: normalize, transpose via per-wave LDS, coalesced 16B stores
  float inv[4];
  #pragma unroll
  for (int r = 0; r < 4; r++) inv[r] = 1.0f / l_run[r];
  u16* Ow = Pw;   // reuse per-wave region: [16 rows][64 d] stride 72
  #pragma unroll
  for (int nt = 0; nt < 4; nt++)
    #pragma unroll
    for (int r = 0; r < 4; r++)
      Ow[(qd * 4 + r) * 72 + nt * 16 + lr] = f2bf(o[nt][r] * inv[r]);
  #pragma unroll
  for (int it = 0; it < 2; it++) {
    int row = it * 8 + (lane >> 3);
    int seg = lane & 7;
    bf16x8 val = *(const bf16x8*)&Ow[row * 72 + seg * 8];
    *(bf16x8*)(attn16 + ((size_t)b * 512 + qrb + row) * 1024 + h * 64 + seg * 8) = val;
  }
}

// ---------------------------------------------------------------- launch
extern "C" void kernel_launch(void* const* d_in, const int* in_sizes, int n_in,
                              void* d_out, int out_size, void* d_ws, size_t ws_size,
                              hipStream_t stream) {
  const float* hR  = (const float*)d_in[0];
  const float* R   = (const float*)d_in[1];
  const float* Wq  = (const float*)d_in[2];
  const float* Wk  = (const float*)d_in[3];
  const float* Wv  = (const float*)d_in[4];
  const float* Wo  = (const float*)d_in[5];
  const float* wsm = (const float*)d_in[6];
  float* out = (float*)d_out;

  const size_t NE = 16777216;   // 16384 x 1024
  u16* ws16   = (u16*)d_ws;
  u16* hR16   = ws16;
  u16* attn16 = ws16;           // reuses hR16 (consumed by QKV GEMM)
  u16* q16    = ws16 + NE;
  u16* k16    = ws16 + 2 * NE;
  u16* v16    = ws16 + 3 * NE;
  u16* vt16   = ws16 + 4 * NE;
  u16* Wq16   = ws16 + 5 * NE;
  u16* Wk16   = Wq16 + 1048576;
  u16* Wv16   = Wk16 + 1048576;
  u16* Wo16   = Wv16 + 1048576;
  u16* sim16  = Wo16 + 1048576;              // 512*512 bf16
  float* Rn   = (float*)(sim16 + 262144);    // 512*256 fp32

  convert_kernel<<<20480, 256, 0, stream>>>(hR, Wq, Wk, Wv, Wo,
                                            hR16, Wq16, Wk16, Wv16, Wo16);
  rnorm_kernel<<<512, 64, 0, stream>>>(R, Rn);
  sim_kernel<<<32, 256, 0, stream>>>(Rn, sim16);
  gemm_kernel<0><<<dim3(128, 24), 256, 0, stream>>>(hR16, Wq16, Wk16, Wv16,
                                                    q16, k16, v16, nullptr);
  vtrans_kernel<<<dim3(8, 512), 256, 0, stream>>>(v16, vt16);
  attn_kernel<<<4096, 256, 0, stream>>>(q16, k16, vt16, sim16, wsm, attn16);
  gemm_kernel<1><<<dim3(128, 8), 256, 0, stream>>>(attn16, Wo16, nullptr, nullptr,
                                                   nullptr, nullptr, nullptr, out);
}

// Round 4
// 454.352 us; speedup vs baseline: 1.1152x; 1.0977x over previous
//
#include <hip/hip_runtime.h>

#define SEQK 512
#define NH 16
#define HD 64
#define RD 1024
#define BBATCH 32
#define QK_SCALE 0.125f        // 1/sqrt(64)
#define LOG2E 1.4426950408889634f

typedef unsigned short u16;
typedef unsigned int u32;
using bf16x8 = __attribute__((ext_vector_type(8))) short;
using f32x4  = __attribute__((ext_vector_type(4))) float;
using f32x16 = __attribute__((ext_vector_type(16))) float;

__device__ __forceinline__ u16 f2bf(float f) {
  unsigned u = __float_as_uint(f);
  u += 0x7FFFu + ((u >> 16) & 1u);   // round-to-nearest-even
  return (u16)(u >> 16);
}
__device__ __forceinline__ float bf2f(u16 v) {
  return __uint_as_float(((unsigned)v) << 16);
}
// 2^x in one VALU op (inputs are pre-scaled by LOG2E upstream)
__device__ __forceinline__ float fexp2(float x) {
  float r;
  asm("v_exp_f32 %0, %1" : "=v"(r) : "v"(x));
  return r;
}
// packed f32x2 -> bf16x2 (RNE), lo in [15:0], hi in [31:16]  (m240 recipe)
__device__ __forceinline__ u32 pkbf(float lo, float hi) {
  u32 r;
  asm("v_cvt_pk_bf16_f32 %0, %1, %2" : "=v"(r) : "v"(lo), "v"(hi));
  return r;
}
// swap a's upper 32 lanes with b's lower 32 lanes (gfx950 permlane32_swap):
// lane<32: a=own, b=partner's a ; lane>=32: a=partner's b, b=own.
__device__ __forceinline__ void plswap(u32& a, u32& b) {
#if __has_builtin(__builtin_amdgcn_permlane32_swap)
  typedef int v2i __attribute__((ext_vector_type(2)));
  v2i r = __builtin_amdgcn_permlane32_swap((int)a, (int)b, false, false);
  a = (u32)r[0]; b = (u32)r[1];
#else
  asm volatile("v_permlane32_swap_b32 %0, %1" : "+v"(a), "+v"(b));
#endif
}

__device__ __forceinline__ void async_cp16(const void* g, void* l) {
  __builtin_amdgcn_global_load_lds(
      (__attribute__((address_space(1))) void*)(void*)g,
      (__attribute__((address_space(3))) void*)l,
      16, 0, 0);
}

// ---------------------------------------------------------------- convert
__global__ void convert_kernel(const float* __restrict__ hR,
                               const float* __restrict__ Wq, const float* __restrict__ Wk,
                               const float* __restrict__ Wv, const float* __restrict__ Wo,
                               u16* __restrict__ hR16,
                               u16* __restrict__ Wq16, u16* __restrict__ Wk16,
                               u16* __restrict__ Wv16, u16* __restrict__ Wo16) {
  size_t i4 = (size_t)blockIdx.x * blockDim.x + threadIdx.x;
  size_t e = i4 * 4;
  const float* src; u16* dst; size_t off;
  if (e < 16777216u) { src = hR; dst = hR16; off = e; }
  else {
    size_t r = e - 16777216u;
    int w = (int)(r >> 20);
    off = r & 1048575u;
    src = (w == 0 ? Wq : w == 1 ? Wk : w == 2 ? Wv : Wo);
    dst = (w == 0 ? Wq16 : w == 1 ? Wk16 : w == 2 ? Wv16 : Wo16);
  }
  float4 v = *(const float4*)(src + off);
  ushort4 o;
  o.x = f2bf(v.x); o.y = f2bf(v.y); o.z = f2bf(v.z); o.w = f2bf(v.w);
  *(ushort4*)(dst + off) = o;
}

// ---------------------------------------------------------------- R normalize
__global__ void rnorm_kernel(const float* __restrict__ R, float* __restrict__ Rn) {
  int row = blockIdx.x;
  int lane = threadIdx.x;
  float4 v = *(const float4*)(R + (size_t)row * 256 + lane * 4);
  float ss = v.x * v.x + v.y * v.y + v.z * v.z + v.w * v.w;
  for (int off = 32; off; off >>= 1) ss += __shfl_xor(ss, off);
  float s = 1.0f / fmaxf(sqrtf(ss), 1e-12f);
  float4 o = {v.x * s, v.y * s, v.z * s, v.w * s};
  *(float4*)(Rn + (size_t)row * 256 + lane * 4) = o;
}

// ---------------------------------------------------------------- sim = Rn @ Rn^T  (bf16 out)
__global__ void sim_kernel(const float* __restrict__ Rn, u16* __restrict__ sim16) {
  __shared__ float Rl[16 * 256];
  int i0 = blockIdx.x * 16;
  int t = threadIdx.x;
  #pragma unroll
  for (int i = 0; i < 4; i++) {
    int f = t + i * 256;
    *(float4*)&Rl[f * 4] = *(const float4*)(Rn + (size_t)i0 * 256 + f * 4);
  }
  __syncthreads();
  for (int jj = 0; jj < 2; jj++) {
    int j = jj * 256 + t;
    float acc[16];
    #pragma unroll
    for (int i = 0; i < 16; i++) acc[i] = 0.f;
    for (int c = 0; c < 64; c++) {
      float4 rv = *(const float4*)(Rn + (size_t)j * 256 + c * 4);
      #pragma unroll
      for (int i = 0; i < 16; i++) {
        float4 a = *(const float4*)&Rl[i * 256 + c * 4];
        acc[i] += a.x * rv.x + a.y * rv.y + a.z * rv.z + a.w * rv.w;
      }
    }
    #pragma unroll
    for (int i = 0; i < 16; i++) sim16[(size_t)(i0 + i) * 512 + j] = f2bf(acc[i]);
  }
}

// ---------------------------------------------------------------- GEMM (bf16 MFMA)
template <int MODE>
__global__ __launch_bounds__(256)
void gemm_kernel(const u16* __restrict__ A,
                 const u16* __restrict__ B0, const u16* __restrict__ B1,
                 const u16* __restrict__ B2,
                 u16* __restrict__ q16, u16* __restrict__ k16, u16* __restrict__ v16,
                 float* __restrict__ outF) {
  __shared__ u16 Alds[128 * 32];
  __shared__ u16 Blds[128 * 32];
  int tid = threadIdx.x;
  int wave = tid >> 6, lane = tid & 63;
  int wm = wave & 1, wn = wave >> 1;
  int lr = lane & 15, qd = lane >> 4;
  int mb = blockIdx.x * 128;
  int ny = blockIdx.y;

  const u16* Bmat;
  int nbmat;
  if (MODE == 0) {
    int wsel = ny >> 3;
    Bmat = (wsel == 0 ? B0 : wsel == 1 ? B1 : B2);
    nbmat = (ny & 7) * 128;
  } else {
    Bmat = B0;
    nbmat = ny * 128;
  }

  f32x4 zero = {0.f, 0.f, 0.f, 0.f};
  f32x4 acc[4][4];
  #pragma unroll
  for (int i = 0; i < 4; i++)
    #pragma unroll
    for (int j = 0; j < 4; j++) acc[i][j] = zero;

  for (int kb = 0; kb < 1024; kb += 32) {
    #pragma unroll
    for (int j = 0; j < 2; j++) {
      int r = (wave * 2 + j) * 16 + (lane >> 2);
      int c = (lane & 3) ^ ((r >> 1) & 3);
      async_cp16(A + (size_t)(mb + r) * 1024 + kb + c * 8,
                 &Alds[(wave * 2 + j) * 512]);
      async_cp16(Bmat + (size_t)(nbmat + r) * 1024 + kb + c * 8,
                 &Blds[(wave * 2 + j) * 512]);
    }
    __syncthreads();

    bf16x8 af[4], bf[4];
    #pragma unroll
    for (int mi = 0; mi < 4; mi++) {
      int ra = wm * 64 + mi * 16 + lr;
      af[mi] = *(const bf16x8*)&Alds[ra * 32 + ((qd ^ ((ra >> 1) & 3)) << 3)];
      int rb = wn * 64 + mi * 16 + lr;
      bf[mi] = *(const bf16x8*)&Blds[rb * 32 + ((qd ^ ((rb >> 1) & 3)) << 3)];
    }
    #pragma unroll
    for (int mi = 0; mi < 4; mi++)
      #pragma unroll
      for (int ni = 0; ni < 4; ni++)
        acc[mi][ni] = __builtin_amdgcn_mfma_f32_16x16x32_bf16(af[mi], bf[ni],
                                                              acc[mi][ni], 0, 0, 0);
    __syncthreads();
  }

  if (MODE == 0) {
    int wsel = ny >> 3;
    u16* dst = (wsel == 0 ? q16 : wsel == 1 ? k16 : v16);
    // Q gets 1/sqrt(D) * log2(e): scores come out in the exp2 domain.
    float scl = (wsel == 0) ? QK_SCALE * LOG2E : 1.0f;
    #pragma unroll
    for (int mi = 0; mi < 4; mi++) {
      int m = mb + wm * 64 + mi * 16 + qd * 4;
      int b = m >> 9, kk = m & 511;
      #pragma unroll
      for (int ni = 0; ni < 4; ni++) {
        int n = nbmat + wn * 64 + ni * 16 + lr;
        int h = n >> 6, d = n & 63;
        u16* p = dst + ((size_t)(b * 16 + h) * 512 + kk) * 64 + d;
        #pragma unroll
        for (int r = 0; r < 4; r++) p[(size_t)r * 64] = f2bf(acc[mi][ni][r] * scl);
      }
    }
  } else {
    #pragma unroll
    for (int mi = 0; mi < 4; mi++) {
      int m = mb + wm * 64 + mi * 16 + qd * 4;
      #pragma unroll
      for (int ni = 0; ni < 4; ni++) {
        int n = ny * 128 + wn * 64 + ni * 16 + lr;
        #pragma unroll
        for (int r = 0; r < 4; r++) outF[(size_t)(m + r) * 1024 + n] = acc[mi][ni][r];
      }
    }
  }
}

// ---------------------------------------------------------------- V transpose
__global__ void vtrans_kernel(const u16* __restrict__ v16, u16* __restrict__ vt16) {
  __shared__ u16 tile[64 * 72];
  int kt = blockIdx.x;
  int bh = blockIdx.y;
  int t = threadIdx.x;
  const u16* src = v16 + ((size_t)bh * 512 + kt * 64) * 64;
  #pragma unroll
  for (int j = 0; j < 2; j++) {
    int linear = j * 2048 + t * 8;
    int kr = linear >> 6, d0 = linear & 63;
    bf16x8 vv = *(const bf16x8*)(src + (size_t)kr * 64 + d0);
    #pragma unroll
    for (int e = 0; e < 8; e++) tile[kr * 72 + d0 + e] = (u16)vv[e];
  }
  __syncthreads();
  #pragma unroll
  for (int j = 0; j < 2; j++) {
    int linear = j * 2048 + t * 8;
    int dr = linear >> 6, k0 = linear & 63;
    bf16x8 ov;
    #pragma unroll
    for (int e = 0; e < 8; e++) ov[e] = (short)tile[(k0 + e) * 72 + dr];
    *(bf16x8*)(vt16 + ((size_t)bh * 64 + dr) * 512 + kt * 64 + k0) = ov;
  }
}

// ---------------------------------------------------------------- fused attention v6b
// R2 post-mortem: pipeline surgery (v4/v5) moved nothing -> the stall is the
// serial softmax/P-path: 16 shfl_xor (LDS-latency chains) + 128 f2bf VALU +
// 32 ds_write_b16 + 4 ds_read_b128 per chunk between the MFMA clusters.
// v6 = m214-v22 structure in plain HIP (T12): 32x32x16 MFMA, SWAPPED QK^T
// (S^T = mfma(K,Q)) so each lane owns one q-column with k-values of a
// subtile in registers:
//  - row max/sum: in-lane reduce + ONE permlane32_swap per stat vs 16 shfls.
//  - P -> PV fragment: 16 v_cvt_pk_bf16_f32 + 8 permlane32_swap per chunk,
//    NO P LDS round-trip. Word w of B-frag step ks needs kk=8m+2w+{0,1},
//    m=2ks+hi; element e comes from reg i=(m&3)*4+(e&3) of lane hi_owner=e>>2
//    in s[m>>2]; pair (a,b)=(pk[4g+t],pk[4g+4+t]) + one swap delivers words
//    (w=t, w=t+2) for BOTH half-waves.
//  - PV computes O^T = mfma(V^T, P^T): output col = q = lane&31 -> alpha/l
//    rescale is lane-local scalars.
// v6b: permlane via __builtin_amdgcn_permlane32_swap (guide-verified) instead
// of raw asm — the one unverified construct in v6's failed compile/run.
// LDS 32KB (K/V dbuf, KVBLK=64, no P buffer) -> 3 blocks/CU. Keeps v5's
// bias-first / counted-vmcnt ordering + 1 barrier per chunk + setprio.
__global__ __launch_bounds__(256, 3)
void attn_kernel(const u16* __restrict__ q16, const u16* __restrict__ k16,
                 const u16* __restrict__ vt16, const u16* __restrict__ sim16,
                 const float* __restrict__ wsim, u16* __restrict__ attn16) {
  __shared__ u16 smem[16384];   // 32 KB: K dbuf [2][64*64] + Vt dbuf [2][64*64]

  int id = blockIdx.x;
  int xcd = id & 7;
  int j = id >> 3;
  int qt = j & 3;
  int bh = xcd * 64 + (j >> 2);
  int b = bh >> 4, h = bh & 15;

  int tid = threadIdx.x;
  int wave = tid >> 6, lane = tid & 63;
  int l31 = lane & 31, hi = lane >> 5;
  int qb = qt * 128 + wave * 32;        // this wave's 32 q rows

  // Q fragments (B-operand): lane(q=l31,hi) holds Q[qb+l31][ds*16+hi*8+e]
  const u16* qp = q16 + ((size_t)bh * 512 + qb + l31) * 64 + hi * 8;
  bf16x8 aq[4];
  #pragma unroll
  for (int ds = 0; ds < 4; ds++) aq[ds] = *(const bf16x8*)(qp + ds * 16);

  float ws = wsim[h] * LOG2E;           // bias in exp2 domain

  f32x16 o[2];
  #pragma unroll
  for (int dt = 0; dt < 2; dt++)
    #pragma unroll
    for (int r = 0; r < 16; r++) o[dt][r] = 0.f;
  float m_run = -1e30f, l_run = 0.f;

  const u16* kbase = k16 + (size_t)bh * 512 * 64;
  const u16* vbase = vt16 + (size_t)bh * 64 * 512;

  // stage 64-k chunk into K/V buffers nb (issue only; XOR-8 chunk swizzle)
  auto stage = [&](int nb, int ck) {
    int k0 = ck * 64;
    u16* kd = smem + nb * 4096;
    u16* vd = smem + 8192 + nb * 4096;
    #pragma unroll
    for (int it = 0; it < 2; it++) {
      int idx = it * 256 + wave * 64 + lane;
      int r = idx >> 3, c8 = idx & 7;
      async_cp16(kbase + (size_t)(k0 + r) * 64 + ((c8 ^ (r & 7)) << 3),
                 kd + (it * 256 + wave * 64) * 8);
    }
    #pragma unroll
    for (int it = 0; it < 2; it++) {
      int idx = it * 256 + wave * 64 + lane;
      int dr = idx >> 3, c8 = idx & 7;
      async_cp16(vbase + (size_t)dr * 512 + k0 + ((c8 ^ (dr & 7)) << 3),
                 vd + (it * 256 + wave * 64) * 8);
    }
  };

  stage(0, 0);
  __syncthreads();

  int cur = 0;
  for (int ck = 0; ck < 8; ck++) {
    int k0 = ck * 64;

    // ---- bias raw loads FIRST (oldest in vmcnt FIFO): their wait leaves
    //      the stage loads below in flight (counted-vmcnt).
    uint2 braw[8];
    #pragma unroll
    for (int kb = 0; kb < 2; kb++)
      #pragma unroll
      for (int g = 0; g < 4; g++)
        braw[kb * 4 + g] = *(const uint2*)(sim16 + (size_t)(qb + l31) * 512 +
                                           k0 + kb * 32 + g * 8 + hi * 4);
    __builtin_amdgcn_sched_barrier(0);
    if (ck < 7) stage(cur ^ 1, ck + 1);

    const u16* Kc = smem + cur * 4096;
    const u16* Vc = smem + 8192 + cur * 4096;

    // ---- S^T = mfma(K, Q) with bias as C-init
    // C layout: col = q = lane&31, row kk = (r&3) + 8*(r>>2) + 4*hi
    f32x16 s[2];
    __builtin_amdgcn_s_setprio(1);
    #pragma unroll
    for (int kb = 0; kb < 2; kb++) {
      f32x16 acc;
      #pragma unroll
      for (int r = 0; r < 16; r++) {
        u32 w = ((r >> 1) & 1) ? braw[kb * 4 + (r >> 2)].y
                               : braw[kb * 4 + (r >> 2)].x;
        acc[r] = ws * __uint_as_float((r & 1) ? (w & 0xFFFF0000u) : (w << 16));
      }
      int koff = kb * 32 + l31;
      #pragma unroll
      for (int ds = 0; ds < 4; ds++) {
        bf16x8 kf = *(const bf16x8*)&Kc[koff * 64 + (((ds * 2 + hi) ^ (koff & 7)) << 3)];
        acc = __builtin_amdgcn_mfma_f32_32x32x16_bf16(kf, aq[ds], acc, 0, 0, 0);
      }
      s[kb] = acc;
    }
    __builtin_amdgcn_s_setprio(0);

    // ---- online softmax (exp2 domain), lane-local + one swap per stat
    float v8[8];
    #pragma unroll
    for (int i = 0; i < 8; i++)
      v8[i] = fmaxf(fmaxf(s[0][i], s[0][i + 8]), fmaxf(s[1][i], s[1][i + 8]));
    float m_in = fmaxf(fmaxf(fmaxf(v8[0], v8[1]), fmaxf(v8[2], v8[3])),
                       fmaxf(fmaxf(v8[4], v8[5]), fmaxf(v8[6], v8[7])));
    u32 xa = __float_as_uint(m_in), xb = __float_as_uint(m_in);
    plswap(xa, xb);
    float m_tile = fmaxf(__uint_as_float(xa), __uint_as_float(xb));
    float mnew = fmaxf(m_run, m_tile);
    float alpha = fexp2(m_run - mnew);
    m_run = mnew;

    float c0 = 0.f, c1 = 0.f, c2 = 0.f, c3 = 0.f;
    #pragma unroll
    for (int kb = 0; kb < 2; kb++)
      #pragma unroll
      for (int i = 0; i < 16; i++) {
        float e = fexp2(s[kb][i] - mnew);
        s[kb][i] = e;
        if ((i & 3) == 0) c0 += e; else if ((i & 3) == 1) c1 += e;
        else if ((i & 3) == 2) c2 += e; else c3 += e;
      }
    float cs = (c0 + c1) + (c2 + c3);
    u32 ya = __float_as_uint(cs), yb = __float_as_uint(cs);
    plswap(ya, yb);
    float cs_tot = __uint_as_float(ya) + __uint_as_float(yb);
    l_run = l_run * alpha + cs_tot;

    // ---- rescale O, then PV: O^T += mfma(V^T, P^T)
    #pragma unroll
    for (int dt = 0; dt < 2; dt++) o[dt] *= alpha;

    __builtin_amdgcn_s_setprio(1);
    #pragma unroll
    for (int ks = 0; ks < 4; ks++) {
      int kb = ks >> 1, j4 = (ks & 1) * 8;   // j4 = 4*g (hi=0 lanes)
      u32 a0 = pkbf(s[kb][j4 + 0], s[kb][j4 + 1]);
      u32 a1 = pkbf(s[kb][j4 + 2], s[kb][j4 + 3]);
      u32 b0 = pkbf(s[kb][j4 + 4], s[kb][j4 + 5]);
      u32 b1 = pkbf(s[kb][j4 + 6], s[kb][j4 + 7]);
      plswap(a0, b0);
      plswap(a1, b1);
      union { u32 w[4]; bf16x8 v; } U;
      U.w[0] = a0; U.w[1] = a1; U.w[2] = b0; U.w[3] = b1;
      #pragma unroll
      for (int dt = 0; dt < 2; dt++) {
        int dr = dt * 32 + l31;
        bf16x8 vf = *(const bf16x8*)&Vc[dr * 64 + (((ks * 2 + hi) ^ (dr & 7)) << 3)];
        o[dt] = __builtin_amdgcn_mfma_f32_32x32x16_bf16(vf, U.v, o[dt], 0, 0, 0);
      }
    }
    __builtin_amdgcn_s_setprio(0);

    __syncthreads();   // drain prefetch (landed under compute) + buffer safety
    cur ^= 1;
  }

  // ---- epilogue: normalize, per-wave LDS transpose, coalesced 16B stores
  float linv = 1.0f / l_run;
  u16* Ow = smem + wave * 2304;   // [32 q][72 d] u16, 16B-aligned rows
  #pragma unroll
  for (int dt = 0; dt < 2; dt++)
    #pragma unroll
    for (int g = 0; g < 4; g++) {
      u32 w0 = pkbf(o[dt][4 * g + 0] * linv, o[dt][4 * g + 1] * linv);
      u32 w1 = pkbf(o[dt][4 * g + 2] * linv, o[dt][4 * g + 3] * linv);
      uint2 pr; pr.x = w0; pr.y = w1;
      *(uint2*)&Ow[l31 * 72 + dt * 32 + g * 8 + hi * 4] = pr;
    }
  #pragma unroll
  for (int i = 0; i < 4; i++) {
    int idx = i * 64 + lane;
    int row = idx >> 3, seg = idx & 7;
    bf16x8 val = *(const bf16x8*)&Ow[row * 72 + seg * 8];
    *(bf16x8*)(attn16 + ((size_t)b * 512 + qb + row) * 1024 + h * 64 + seg * 8) = val;
  }
}

// ---------------------------------------------------------------- launch
extern "C" void kernel_launch(void* const* d_in, const int* in_sizes, int n_in,
                              void* d_out, int out_size, void* d_ws, size_t ws_size,
                              hipStream_t stream) {
  const float* hR  = (const float*)d_in[0];
  const float* R   = (const float*)d_in[1];
  const float* Wq  = (const float*)d_in[2];
  const float* Wk  = (const float*)d_in[3];
  const float* Wv  = (const float*)d_in[4];
  const float* Wo  = (const float*)d_in[5];
  const float* wsm = (const float*)d_in[6];
  float* out = (float*)d_out;

  const size_t NE = 16777216;   // 16384 x 1024
  u16* ws16   = (u16*)d_ws;
  u16* hR16   = ws16;
  u16* attn16 = ws16;           // reuses hR16 (consumed by QKV GEMM)
  u16* q16    = ws16 + NE;
  u16* k16    = ws16 + 2 * NE;
  u16* v16    = ws16 + 3 * NE;
  u16* vt16   = ws16 + 4 * NE;
  u16* Wq16   = ws16 + 5 * NE;
  u16* Wk16   = Wq16 + 1048576;
  u16* Wv16   = Wk16 + 1048576;
  u16* Wo16   = Wv16 + 1048576;
  u16* sim16  = Wo16 + 1048576;              // 512*512 bf16
  float* Rn   = (float*)(sim16 + 262144);    // 512*256 fp32

  convert_kernel<<<20480, 256, 0, stream>>>(hR, Wq, Wk, Wv, Wo,
                                            hR16, Wq16, Wk16, Wv16, Wo16);
  rnorm_kernel<<<512, 64, 0, stream>>>(R, Rn);
  sim_kernel<<<32, 256, 0, stream>>>(Rn, sim16);
  gemm_kernel<0><<<dim3(128, 24), 256, 0, stream>>>(hR16, Wq16, Wk16, Wv16,
                                                    q16, k16, v16, nullptr);
  vtrans_kernel<<<dim3(8, 512), 256, 0, stream>>>(v16, vt16);
  attn_kernel<<<2048, 256, 0, stream>>>(q16, k16, vt16, sim16, wsm, attn16);
  gemm_kernel<1><<<dim3(128, 8), 256, 0, stream>>>(attn16, Wo16, nullptr, nullptr,
                                                   nullptr, nullptr, nullptr, out);
}